// Round 8
// baseline (50.872 us; speedup 1.0000x reference)
//
#include <hip/hip_runtime.h>

// 2x upsample, binomial blur [1,4,6,4,1]/8 per axis, edge clamp.
// Flat-store rewrite: thread = one w-quad (4 consecutive outputs) of one
// (h) row, for BOTH output d-planes 2a and 2a+1 (shared 9-row input
// neighborhood). Wave lanes are consecutive in flattened (h,w) -> every
// wave-level store is one fully contiguous 1KB span (fill-kernel pattern),
// vs r3's 3x384B discontiguous segments per store instruction.
// Unified weights: per axis even taps (1,6,1), odd taps (0,4,4), one final
// exact *1/512 per output.

typedef float f32x4 __attribute__((ext_vector_type(4)));

constexpr int DIN = 48, HIN = 48, WIN = 48;
constexpr int HW = HIN * WIN;     // 2304 input plane
constexpr int PS = 96 * 96;       // 9216 output plane (floats)

__global__ __launch_bounds__(256) void Upsample2x2x2_kernel(
    const float* __restrict__ x, float* __restrict__ out)
{
    const int p  = blockIdx.x * 256 + threadIdx.x;  // quad index in plane, 0..2303
    const int a  = blockIdx.y;                      // input d; output planes 2a, 2a+1
    const int nc = blockIdx.z;

    const int h    = p / 24;          // output h row 0..95 (const-div -> mulhi)
    const int s    = p - h * 24;      // w-quad 0..23, input w0 = 2s
    const int b    = h >> 1;
    const int hodd = h & 1;

    const float* __restrict__ xb = x + nc * (DIN * HW);

    // d neighbor rows; even plane weights (1,6,1), odd plane (0,4,4)
    const int ii[3] = { a > 0 ? a - 1 : 0, a, a + 1 < DIN ? a + 1 : DIN - 1 };

    // h neighbor rows + weights: even h: (c(b-1),b,c(b+1)) w(1,6,1);
    // odd h: (b, c(b+1), c(b+1)) w(4,4,0)
    const int jb1 = b + 1 < HIN ? b + 1 : HIN - 1;
    const int jj[3] = { hodd ? b : (b > 0 ? b - 1 : 0),
                        hodd ? jb1 : b,
                        jb1 };
    const float hw[3] = { hodd ? 4.f : 1.f, hodd ? 4.f : 6.f, hodd ? 0.f : 1.f };

    // single 16B load per row covering u0..u3 = x[c(w0-1)..c(w0+2)] (r7 trick)
    const bool lo = (s == 0), hi = (s == 23);
    const int base = 2 * s + (lo ? 0 : (hi ? -2 : -1));

    // h-combine raw u-vectors (4 wide) per d-row
    float hc[3][4];
    #pragma unroll
    for (int i = 0; i < 3; i++) {
        const float* __restrict__ xd = xb + ii[i] * HW;
        float a0 = 0.f, a1 = 0.f, a2 = 0.f, a3 = 0.f;
        #pragma unroll
        for (int j = 0; j < 3; j++) {
            const float* __restrict__ row = xd + jj[j] * WIN;
            f32x4 v;
            __builtin_memcpy(&v, row + base, 16);
            float u0 = hi ? v.y : v.x;
            float u1 = lo ? v.x : (hi ? v.z : v.y);
            float u2 = lo ? v.y : (hi ? v.w : v.z);
            float u3 = lo ? v.z : v.w;
            float w = hw[j];
            a0 = fmaf(w, u0, a0);
            a1 = fmaf(w, u1, a1);
            a2 = fmaf(w, u2, a2);
            a3 = fmaf(w, u3, a3);
        }
        hc[i][0] = a0; hc[i][1] = a1; hc[i][2] = a2; hc[i][3] = a3;
    }

    // W-stage per d-row: quad [E(2s), O(2s), E(2s+1), O(2s+1)]
    float Wv[3][4];
    #pragma unroll
    for (int i = 0; i < 3; i++) {
        Wv[i][0] = fmaf(6.f, hc[i][1], hc[i][0]) + hc[i][2];
        Wv[i][1] = (hc[i][1] + hc[i][2]) * 4.f;
        Wv[i][2] = fmaf(6.f, hc[i][2], hc[i][1]) + hc[i][3];
        Wv[i][3] = (hc[i][2] + hc[i][3]) * 4.f;
    }

    // d-combine + one exact *1/512; even plane (1,6,1), odd plane (0,4,4)
    f32x4 e, o;
    e.x = (fmaf(6.f, Wv[1][0], Wv[0][0]) + Wv[2][0]) * (1.f/512);
    e.y = (fmaf(6.f, Wv[1][1], Wv[0][1]) + Wv[2][1]) * (1.f/512);
    e.z = (fmaf(6.f, Wv[1][2], Wv[0][2]) + Wv[2][2]) * (1.f/512);
    e.w = (fmaf(6.f, Wv[1][3], Wv[0][3]) + Wv[2][3]) * (1.f/512);
    o.x = (Wv[1][0] + Wv[2][0]) * (4.f/512);
    o.y = (Wv[1][1] + Wv[2][1]) * (4.f/512);
    o.z = (Wv[1][2] + Wv[2][2]) * (4.f/512);
    o.w = (Wv[1][3] + Wv[2][3]) * (4.f/512);

    float* __restrict__ ob = out + (nc * 96 + 2 * a) * PS;
    __builtin_nontemporal_store(e, reinterpret_cast<f32x4*>(ob + p * 4));
    __builtin_nontemporal_store(o, reinterpret_cast<f32x4*>(ob + PS + p * 4));
}

extern "C" void kernel_launch(void* const* d_in, const int* in_sizes, int n_in,
                              void* d_out, int out_size, void* d_ws, size_t ws_size,
                              hipStream_t stream) {
    const float* x = (const float*)d_in[0];
    float* out = (float*)d_out;
    dim3 grid(9, 48, 64);   // 9*256 = 2304 quads/plane-pair, 48 d-pairs, 64 nc
    Upsample2x2x2_kernel<<<grid, 256, 0, stream>>>(x, out);
}